// Round 1
// baseline (234.792 us; speedup 1.0000x reference)
//
#include <hip/hip_runtime.h>
#include <hip/hip_bf16.h>
#include <cstdint>
#include <cstddef>

// Problem constants
constexpr int T = 8;
constexpr int C = 256;     // feature channels = GEMM K
constexpr int N = 4096;    // H*W pixels per frame
constexpr float TEMP_INV = 14.285714285714286f;  // 1/0.07
constexpr float EPS = 1e-8f;

typedef __bf16 bf16;
typedef __bf16 bf16x8 __attribute__((ext_vector_type(8)));
typedef float floatx4 __attribute__((ext_vector_type(4)));

// ---------------------------------------------------------------------------
// async global->LDS, 16B per lane, wave-uniform LDS base + lane*16
__device__ __forceinline__ void async_copy16(const bf16* g, bf16* l) {
    __builtin_amdgcn_global_load_lds((const __attribute__((address_space(1))) void*)g,
                                     (__attribute__((address_space(3))) void*)l,
                                     16, 0, 0);
}

// ---------------------------------------------------------------------------
__global__ void zero_kernel(float* neg, int* cnts) {
    int i = blockIdx.x * blockDim.x + threadIdx.x;
    if (i < T * N) neg[i] = 0.0f;
    if (i < 16) cnts[i] = 0;
}

// ---------------------------------------------------------------------------
// Per-frame dice deviation -> use_curr flag
__global__ void stats_kernel(const float* __restrict__ cur,
                             const float* __restrict__ hist,
                             float* __restrict__ flag) {
    int t = blockIdx.x;
    int tid = threadIdx.x;
    float s1 = 0.f, sc = 0.f, sh = 0.f;
    for (int k = tid; k < N; k += 256) {
        float c = cur[t * N + k] > 0.5f ? 1.f : 0.f;
        float h = hist[t * N + k] > 0.5f ? 1.f : 0.f;
        s1 += c * h; sc += c; sh += h;
    }
    for (int o = 32; o > 0; o >>= 1) {
        s1 += __shfl_down(s1, o);
        sc += __shfl_down(sc, o);
        sh += __shfl_down(sh, o);
    }
    __shared__ float r1[4], r2[4], r3[4];
    int w = tid >> 6;
    if ((tid & 63) == 0) { r1[w] = s1; r2[w] = sc; r3[w] = sh; }
    __syncthreads();
    if (tid == 0) {
        float e1 = r1[0] + r1[1] + r1[2] + r1[3];
        float scs = r2[0] + r2[1] + r2[2] + r2[3];
        float shs = r3[0] + r3[1] + r3[2] + r3[3];
        float e2 = scs + shs;
        float m1 = (2.f * e1 + EPS) / (e2 + EPS);
        float m2 = (e1 + EPS) / (e2 - e1 + EPS);
        float dev = 1.f - 0.5f * (m1 + m2);
        flag[t] = (dev <= 0.0f) ? 1.f : 0.f;
    }
}

// ---------------------------------------------------------------------------
// labels -> d_out[0..T*N), bg mask (1.0 = background), fg/bg counts
__global__ void labels_kernel(const float* __restrict__ cur,
                              const float* __restrict__ hist,
                              const float* __restrict__ flag,
                              float* __restrict__ out_labels,
                              float* __restrict__ bgmask,
                              int* __restrict__ nfg, int* __restrict__ nbg) {
    int i = blockIdx.x * 256 + threadIdx.x;   // 0 .. T*N
    int t = i >> 12;                           // N = 4096
    float lab = (flag[t] != 0.f) ? cur[i] : hist[i];
    out_labels[i] = lab;
    bool fg = lab > 0.5f;
    bgmask[i] = fg ? 0.f : 1.f;
    unsigned long long b = __ballot(fg);
    if ((threadIdx.x & 63) == 0) {            // frame boundary is wave-aligned
        int cfg = __popcll(b);
        atomicAdd(&nfg[t], cfg);
        atomicAdd(&nbg[t], 64 - cfg);
    }
}

// ---------------------------------------------------------------------------
// Normalize features and transpose [T][C][N] -> bf16 [T][N][C]; also the
// diagonal dot (sum f_hat^2) for pos.
__global__ __launch_bounds__(256) void normalize_kernel(const float* __restrict__ feat,
                                                        bf16* __restrict__ fhat,
                                                        float* __restrict__ posdot) {
    __shared__ float tile[64 * 257];   // [n][c], pad 257 -> conflict-free col writes
    __shared__ float partial[256];
    __shared__ float rnorm_s[64];
    int t = blockIdx.x >> 6;           // 8 frames
    int n0 = (blockIdx.x & 63) * 64;   // 64 pixel rows per block
    int tid = threadIdx.x;
    int lane63 = tid & 63;
    int w = tid >> 6;
    const float* fb = feat + (size_t)t * C * N;
    // coalesced load: wave w reads channel rows c = w*64+it, 64 pixels each
    for (int it = 0; it < 64; ++it) {
        int c = w * 64 + it;
        tile[lane63 * 257 + c] = fb[(size_t)c * N + n0 + lane63];
    }
    __syncthreads();
    { // sum of squares per pixel
        int n = tid & 63, cp = tid >> 6;
        const float* row = &tile[n * 257 + cp * 64];
        float s = 0.f;
        for (int c = 0; c < 64; ++c) { float v = row[c]; s += v * v; }
        partial[tid] = s;
    }
    __syncthreads();
    if (tid < 64) {
        float s = partial[tid] + partial[tid + 64] + partial[tid + 128] + partial[tid + 192];
        float nrm = sqrtf(s);
        float r = 1.f / fmaxf(nrm, 1e-12f);
        rnorm_s[tid] = r;
        posdot[t * N + n0 + tid] = s * r * r;   // = sum of normalized squares
    }
    __syncthreads();
    // contiguous bf16 store: the 64x256 tile is one contiguous region in [T][N][C]
    bf16* ob = fhat + ((size_t)t * N + n0) * C;
    for (int it = 0; it < 8; ++it) {
        int l = it * 256 + tid;       // short8 index, 0..2047
        int n = l >> 5;
        int c = (l & 31) * 8;
        float r = rnorm_s[n];
        const float* src = &tile[n * 257 + c];
        bf16x8 v;
        for (int j = 0; j < 8; ++j) v[j] = (bf16)(src[j] * r);
        *(bf16x8*)(ob + l * 8) = v;
    }
}

// ---------------------------------------------------------------------------
// Fused sim GEMM + exp + bg-masked row reduction.
// Grid: (colTile=32, rowTile=32, t=8), 256 threads = 4 waves, 128x128 tile, K=256.
// LDS staging via global_load_lds width-16 with XOR-chunk swizzle:
//   LDS[row][ch'] (16B chunks, 8 per 64-wide row) holds global chunk ch' ^ (row&7).
__global__ __launch_bounds__(256, 2) void sim_kernel(const bf16* __restrict__ fhat,
                                                     const float* __restrict__ bgmask,
                                                     float* __restrict__ neg) {
    __shared__ bf16 a_lds[128 * 64];
    __shared__ bf16 b_lds[128 * 64];
    int t = blockIdx.z;
    int rowbase = blockIdx.y * 128;
    int colbase = blockIdx.x * 128;
    int tid = threadIdx.x;
    int lane = tid & 63;
    int w = tid >> 6;
    const bf16* fb = fhat + (size_t)t * N * C;

    int ch = (lane & 7) ^ (lane >> 3);   // swizzled global chunk this lane fetches
    int r0w = (w & 1) * 64;
    int c0w = (w >> 1) * 64;

    floatx4 acc[4][4];
    for (int i = 0; i < 4; ++i)
        for (int j = 0; j < 4; ++j)
            acc[i][j] = (floatx4){0.f, 0.f, 0.f, 0.f};

    for (int ks = 0; ks < 4; ++ks) {
        int k0 = ks * 64;
        __syncthreads();
        // stage A(128 rows) and B(128 cols) x 64 K as 16 x 1KB chunks each
        for (int s = 0; s < 4; ++s) {
            int q = w * 4 + s;                 // 0..15
            int row_l = q * 8 + (lane >> 3);   // 0..127 local row
            const bf16* ga = fb + (size_t)(rowbase + row_l) * C + k0 + ch * 8;
            async_copy16(ga, &a_lds[q * 512]);
            const bf16* gb = fb + (size_t)(colbase + row_l) * C + k0 + ch * 8;
            async_copy16(gb, &b_lds[q * 512]);
        }
        __syncthreads();   // compiler drains vmcnt before barrier
        for (int kk = 0; kk < 64; kk += 32) {
            int quad = lane >> 4;
            int chread = (kk >> 3) + quad;     // global chunk wanted (0..7)
            bf16x8 af[4], bfr[4];
            for (int i = 0; i < 4; ++i) {
                int r = r0w + 16 * i + (lane & 15);
                int chs = chread ^ (r & 7);
                af[i] = *(const bf16x8*)&a_lds[r * 64 + chs * 8];
            }
            for (int j = 0; j < 4; ++j) {
                int cidx = c0w + 16 * j + (lane & 15);
                int chs = chread ^ (cidx & 7);
                bfr[j] = *(const bf16x8*)&b_lds[cidx * 64 + chs * 8];
            }
            for (int i = 0; i < 4; ++i)
                for (int j = 0; j < 4; ++j)
                    acc[i][j] = __builtin_amdgcn_mfma_f32_16x16x32_bf16(af[i], bfr[j], acc[i][j], 0, 0, 0);
        }
    }

    // epilogue: exp, bg-mask, row-sum (16 cols per tile live on lanes sharing quad)
    float bgv[4];
    for (int j = 0; j < 4; ++j)
        bgv[j] = bgmask[t * N + colbase + c0w + 16 * j + (lane & 15)];

    int quad = lane >> 4;
    for (int i = 0; i < 4; ++i) {
        for (int reg = 0; reg < 4; ++reg) {
            float msum = 0.f;
            for (int j = 0; j < 4; ++j)
                msum += __expf(acc[i][j][reg] * TEMP_INV) * bgv[j];
            msum += __shfl_xor(msum, 1);
            msum += __shfl_xor(msum, 2);
            msum += __shfl_xor(msum, 4);
            msum += __shfl_xor(msum, 8);
            if ((lane & 15) == 0) {
                int row = rowbase + r0w + 16 * i + quad * 4 + reg;
                atomicAdd(&neg[t * N + row], msum);
            }
        }
    }
}

// ---------------------------------------------------------------------------
__global__ void loss_frame_kernel(const float* __restrict__ labels,
                                  const float* __restrict__ negbuf,
                                  const float* __restrict__ posdot,
                                  const int* __restrict__ nfg,
                                  const int* __restrict__ nbg,
                                  float* __restrict__ framebuf) {
    int t = blockIdx.x;
    int tid = threadIdx.x;
    float s = 0.f;
    for (int k = tid; k < N; k += 256) {
        float lab = labels[t * N + k];
        if (lab > 0.5f) {
            float pos = __expf(posdot[t * N + k] * TEMP_INV);
            float ng = negbuf[t * N + k];
            // -log(pos/(pos+neg+eps)) = log((pos+neg+eps)/pos)
            s += logf((pos + ng + EPS) / pos);
        }
    }
    for (int o = 32; o > 0; o >>= 1) s += __shfl_down(s, o);
    __shared__ float r[4];
    if ((tid & 63) == 0) r[tid >> 6] = s;
    __syncthreads();
    if (tid == 0) {
        float tot = r[0] + r[1] + r[2] + r[3];
        int f = nfg[t];
        float fl = tot / fmaxf((float)f, 1.f);
        float valid = (f > 0 && nbg[t] > 0) ? 1.f : 0.f;
        framebuf[t] = fl * valid;
        framebuf[8 + t] = valid;
    }
}

__global__ void loss_final_kernel(const float* __restrict__ framebuf,
                                  float* __restrict__ out_loss) {
    if (threadIdx.x == 0) {
        float s = 0.f, v = 0.f;
        for (int t = 0; t < T; ++t) { s += framebuf[t]; v += framebuf[8 + t]; }
        out_loss[0] = (v > 0.f) ? s / fmaxf(v, 1.f) : 0.f;
    }
}

// ---------------------------------------------------------------------------
extern "C" void kernel_launch(void* const* d_in, const int* in_sizes, int n_in,
                              void* d_out, int out_size, void* d_ws, size_t ws_size,
                              hipStream_t stream) {
    const float* cur  = (const float*)d_in[0];
    const float* hist = (const float*)d_in[1];
    const float* feat = (const float*)d_in[2];
    // d_in[3] = epoch, unused (reference always takes the epoch>=1 path)
    float* out = (float*)d_out;   // labels[32768] ++ loss[1]

    char* ws = (char*)d_ws;
    bf16*  fhat    = (bf16*)ws;                       // 8*4096*256 bf16 = 16 MiB
    float* negbuf  = (float*)(ws + 16777216);         // 32768 f32
    float* posdot  = (float*)(ws + 16908288);         // 32768 f32
    float* bgmask  = (float*)(ws + 17039360);         // 32768 f32
    float* flag    = (float*)(ws + 17170432);         // 8 f32
    int*   nfg     = (int*)(ws + 17170432 + 64);      // 8 + 8 ints (nbg follows)
    int*   nbg     = nfg + 8;
    float* framebuf = (float*)(nbg + 8);              // 16 f32

    zero_kernel<<<128, 256, 0, stream>>>(negbuf, nfg);
    stats_kernel<<<8, 256, 0, stream>>>(cur, hist, flag);
    labels_kernel<<<128, 256, 0, stream>>>(cur, hist, flag, out, bgmask, nfg, nbg);
    normalize_kernel<<<512, 256, 0, stream>>>(feat, fhat, posdot);
    dim3 g(32, 32, 8);
    sim_kernel<<<g, 256, 0, stream>>>(fhat, bgmask, negbuf);
    loss_frame_kernel<<<8, 256, 0, stream>>>(out, negbuf, posdot, nfg, nbg, framebuf);
    loss_final_kernel<<<1, 64, 0, stream>>>(framebuf, out + 32768);
}

// Round 2
// 170.636 us; speedup vs baseline: 1.3760x; 1.3760x over previous
//
#include <hip/hip_runtime.h>
#include <hip/hip_bf16.h>
#include <cstdint>
#include <cstddef>

// Problem constants
constexpr int T = 8;
constexpr int C = 256;     // feature channels = GEMM K
constexpr int N = 4096;    // H*W pixels per frame
constexpr float TEMP_INV = 14.285714285714286f;  // 1/0.07
constexpr float EPS = 1e-8f;

typedef __bf16 bf16;
typedef __bf16 bf16x8 __attribute__((ext_vector_type(8)));
typedef float floatx4 __attribute__((ext_vector_type(4)));

// ---------------------------------------------------------------------------
// async global->LDS, 16B per lane, wave-uniform LDS base + lane*16
__device__ __forceinline__ void async_copy16(const bf16* g, bf16* l) {
    __builtin_amdgcn_global_load_lds((const __attribute__((address_space(1))) void*)g,
                                     (__attribute__((address_space(3))) void*)l,
                                     16, 0, 0);
}

// ---------------------------------------------------------------------------
// Per-frame dice deviation -> use_curr flag; also zero the compaction counters.
__global__ void stats_kernel(const float* __restrict__ cur,
                             const float* __restrict__ hist,
                             float* __restrict__ flag,
                             int* __restrict__ nfg, int* __restrict__ nbg) {
    int t = blockIdx.x;
    int tid = threadIdx.x;
    float s1 = 0.f, sc = 0.f, sh = 0.f;
    for (int k = tid; k < N; k += 256) {
        float c = cur[t * N + k] > 0.5f ? 1.f : 0.f;
        float h = hist[t * N + k] > 0.5f ? 1.f : 0.f;
        s1 += c * h; sc += c; sh += h;
    }
    for (int o = 32; o > 0; o >>= 1) {
        s1 += __shfl_down(s1, o);
        sc += __shfl_down(sc, o);
        sh += __shfl_down(sh, o);
    }
    __shared__ float r1[4], r2[4], r3[4];
    int w = tid >> 6;
    if ((tid & 63) == 0) { r1[w] = s1; r2[w] = sc; r3[w] = sh; }
    __syncthreads();
    if (tid == 0) {
        float e1 = r1[0] + r1[1] + r1[2] + r1[3];
        float scs = r2[0] + r2[1] + r2[2] + r2[3];
        float shs = r3[0] + r3[1] + r3[2] + r3[3];
        float e2 = scs + shs;
        float m1 = (2.f * e1 + EPS) / (e2 + EPS);
        float m2 = (e1 + EPS) / (e2 - e1 + EPS);
        float dev = 1.f - 0.5f * (m1 + m2);
        flag[t] = (dev <= 0.0f) ? 1.f : 0.f;
        nfg[t] = 0;
        nbg[t] = 0;
    }
}

// ---------------------------------------------------------------------------
// labels -> d_out[0..T*N), zero negbuf, and build per-frame compacted
// fg / bg pixel index lists (order arbitrary; all downstream uses are sums).
// Grid: 8 blocks (one per frame) x 1024 threads.
__global__ void labels_kernel(const float* __restrict__ cur,
                              const float* __restrict__ hist,
                              const float* __restrict__ flag,
                              float* __restrict__ out_labels,
                              float* __restrict__ negbuf,
                              unsigned short* __restrict__ fgidx,
                              unsigned short* __restrict__ bgidx,
                              int* __restrict__ nfg, int* __restrict__ nbg) {
    int t = blockIdx.x;
    int tid = threadIdx.x;
    int lane = tid & 63;
    bool use_curr = flag[t] != 0.f;
    for (int it = 0; it < 4; ++it) {
        int p = it * 1024 + tid;                 // pixel 0..4095
        int gi = t * N + p;
        float lab = use_curr ? cur[gi] : hist[gi];
        out_labels[gi] = lab;
        negbuf[gi] = 0.f;
        bool fg = lab > 0.5f;
        unsigned long long b = __ballot(fg);
        unsigned long long below = (lane == 0) ? 0ull : (b << (64 - lane)) >> (64 - lane);
        // rank among set lanes below me
        unsigned long long lowmask = (lane == 63) ? 0x7fffffffffffffffull
                                                  : ((1ull << lane) - 1ull);
        int rank_fg = __popcll(b & lowmask);
        int rank_bg = __popcll((~b) & lowmask);
        int cnt_fg = __popcll(b);
        int base_fg = 0, base_bg = 0;
        if (lane == 0) {
            base_fg = atomicAdd(&nfg[t], cnt_fg);
            base_bg = atomicAdd(&nbg[t], 64 - cnt_fg);
        }
        base_fg = __shfl(base_fg, 0);
        base_bg = __shfl(base_bg, 0);
        if (fg) fgidx[t * N + base_fg + rank_fg] = (unsigned short)p;
        else    bgidx[t * N + base_bg + rank_bg] = (unsigned short)p;
        (void)below;
    }
}

// ---------------------------------------------------------------------------
// Normalize features and transpose [T][C][N] -> bf16 [T][N][C]; also the
// diagonal dot (sum f_hat^2) for pos.
__global__ __launch_bounds__(256) void normalize_kernel(const float* __restrict__ feat,
                                                        bf16* __restrict__ fhat,
                                                        float* __restrict__ posdot) {
    __shared__ float tile[64 * 257];   // [n][c], pad 257
    __shared__ float partial[256];
    __shared__ float rnorm_s[64];
    int t = blockIdx.x >> 6;           // 8 frames
    int n0 = (blockIdx.x & 63) * 64;   // 64 pixel rows per block
    int tid = threadIdx.x;
    int lane63 = tid & 63;
    int w = tid >> 6;
    const float* fb = feat + (size_t)t * C * N;
    for (int it = 0; it < 64; ++it) {
        int c = w * 64 + it;
        tile[lane63 * 257 + c] = fb[(size_t)c * N + n0 + lane63];
    }
    __syncthreads();
    { // sum of squares per pixel
        int n = tid & 63, cp = tid >> 6;
        const float* row = &tile[n * 257 + cp * 64];
        float s = 0.f;
        for (int c = 0; c < 64; ++c) { float v = row[c]; s += v * v; }
        partial[tid] = s;
    }
    __syncthreads();
    if (tid < 64) {
        float s = partial[tid] + partial[tid + 64] + partial[tid + 128] + partial[tid + 192];
        float nrm = sqrtf(s);
        float r = 1.f / fmaxf(nrm, 1e-12f);
        rnorm_s[tid] = r;
        posdot[t * N + n0 + tid] = s * r * r;
    }
    __syncthreads();
    bf16* ob = fhat + ((size_t)t * N + n0) * C;
    for (int it = 0; it < 8; ++it) {
        int l = it * 256 + tid;       // short8 index, 0..2047
        int n = l >> 5;
        int c = (l & 31) * 8;
        float r = rnorm_s[n];
        const float* src = &tile[n * 257 + c];
        bf16x8 v;
        for (int j = 0; j < 8; ++j) v[j] = (bf16)(src[j] * r);
        *(bf16x8*)(ob + l * 8) = v;
    }
}

// ---------------------------------------------------------------------------
// Fused sim GEMM + exp + row reduction over COMPACTED fg rows x bg cols.
// Grid: (colTile=32, rowTile=32, t=8); blocks beyond the compacted extents
// early-exit. 256 threads = 4 waves, 128x128 tile, K=256.
// LDS staging via global_load_lds width-16 with XOR-chunk swizzle.
__global__ __launch_bounds__(256, 2) void sim_kernel(const bf16* __restrict__ fhat,
                                                     const unsigned short* __restrict__ fgidx,
                                                     const unsigned short* __restrict__ bgidx,
                                                     const int* __restrict__ nfg,
                                                     const int* __restrict__ nbg,
                                                     float* __restrict__ neg) {
    int t = blockIdx.z;
    int nfgt = nfg[t];
    int nbgt = nbg[t];
    int rowbase = blockIdx.y * 128;
    int colbase = blockIdx.x * 128;
    if (rowbase >= nfgt || colbase >= nbgt) return;

    __shared__ bf16 a_lds[128 * 64];
    __shared__ bf16 b_lds[128 * 64];
    int tid = threadIdx.x;
    int lane = tid & 63;
    int w = tid >> 6;
    const bf16* fb = fhat + (size_t)t * N * C;

    int ch = (lane & 7) ^ (lane >> 3);   // swizzled global chunk this lane fetches
    int r0w = (w & 1) * 64;
    int c0w = (w >> 1) * 64;

    // gathered row base pointers (fixed across K-steps)
    const bf16* arp[4];
    const bf16* brp[4];
    for (int s = 0; s < 4; ++s) {
        int q = w * 4 + s;
        int row_l = q * 8 + (lane >> 3);          // 0..127 local row
        int ra = rowbase + row_l; if (ra >= nfgt) ra = nfgt - 1;
        int rb = colbase + row_l; if (rb >= nbgt) rb = nbgt - 1;
        arp[s] = fb + (size_t)fgidx[t * N + ra] * C + ch * 8;
        brp[s] = fb + (size_t)bgidx[t * N + rb] * C + ch * 8;
    }

    floatx4 acc[4][4];
    for (int i = 0; i < 4; ++i)
        for (int j = 0; j < 4; ++j)
            acc[i][j] = (floatx4){0.f, 0.f, 0.f, 0.f};

    for (int ks = 0; ks < 4; ++ks) {
        int k0 = ks * 64;
        __syncthreads();
        for (int s = 0; s < 4; ++s) {
            int q = w * 4 + s;                 // 0..15
            async_copy16(arp[s] + k0, &a_lds[q * 512]);
            async_copy16(brp[s] + k0, &b_lds[q * 512]);
        }
        __syncthreads();
        for (int kk = 0; kk < 64; kk += 32) {
            int quad = lane >> 4;
            int chread = (kk >> 3) + quad;     // global chunk wanted (0..7)
            bf16x8 af[4], bfr[4];
            for (int i = 0; i < 4; ++i) {
                int r = r0w + 16 * i + (lane & 15);
                int chs = chread ^ (r & 7);
                af[i] = *(const bf16x8*)&a_lds[r * 64 + chs * 8];
            }
            for (int j = 0; j < 4; ++j) {
                int cidx = c0w + 16 * j + (lane & 15);
                int chs = chread ^ (cidx & 7);
                bfr[j] = *(const bf16x8*)&b_lds[cidx * 64 + chs * 8];
            }
            for (int i = 0; i < 4; ++i)
                for (int j = 0; j < 4; ++j)
                    acc[i][j] = __builtin_amdgcn_mfma_f32_16x16x32_bf16(af[i], bfr[j], acc[i][j], 0, 0, 0);
        }
    }

    // epilogue: exp + row-sum; mask padded cols, guard padded rows
    float bgv[4];
    for (int j = 0; j < 4; ++j) {
        int cidx = colbase + c0w + 16 * j + (lane & 15);
        bgv[j] = (cidx < nbgt) ? 1.f : 0.f;
    }

    int quad = lane >> 4;
    for (int i = 0; i < 4; ++i) {
        for (int reg = 0; reg < 4; ++reg) {
            float msum = 0.f;
            for (int j = 0; j < 4; ++j)
                msum += __expf(acc[i][j][reg] * TEMP_INV) * bgv[j];
            msum += __shfl_xor(msum, 1);
            msum += __shfl_xor(msum, 2);
            msum += __shfl_xor(msum, 4);
            msum += __shfl_xor(msum, 8);
            if ((lane & 15) == 0) {
                int row = rowbase + r0w + 16 * i + quad * 4 + reg;   // compacted fg row
                if (row < nfgt) atomicAdd(&neg[t * N + row], msum);
            }
        }
    }
}

// ---------------------------------------------------------------------------
__global__ void loss_frame_kernel(const float* __restrict__ negbuf,
                                  const float* __restrict__ posdot,
                                  const unsigned short* __restrict__ fgidx,
                                  const int* __restrict__ nfg,
                                  const int* __restrict__ nbg,
                                  float* __restrict__ framebuf) {
    int t = blockIdx.x;
    int tid = threadIdx.x;
    int nfgt = nfg[t];
    float s = 0.f;
    for (int k = tid; k < nfgt; k += 256) {
        int pix = fgidx[t * N + k];
        float pos = __expf(posdot[t * N + pix] * TEMP_INV);
        float ng = negbuf[t * N + k];
        s += logf((pos + ng + EPS) / pos);
    }
    for (int o = 32; o > 0; o >>= 1) s += __shfl_down(s, o);
    __shared__ float r[4];
    if ((tid & 63) == 0) r[tid >> 6] = s;
    __syncthreads();
    if (tid == 0) {
        float tot = r[0] + r[1] + r[2] + r[3];
        float fl = tot / fmaxf((float)nfgt, 1.f);
        float valid = (nfgt > 0 && nbg[t] > 0) ? 1.f : 0.f;
        framebuf[t] = fl * valid;
        framebuf[8 + t] = valid;
    }
}

__global__ void loss_final_kernel(const float* __restrict__ framebuf,
                                  float* __restrict__ out_loss) {
    if (threadIdx.x == 0) {
        float s = 0.f, v = 0.f;
        for (int t = 0; t < T; ++t) { s += framebuf[t]; v += framebuf[8 + t]; }
        out_loss[0] = (v > 0.f) ? s / fmaxf(v, 1.f) : 0.f;
    }
}

// ---------------------------------------------------------------------------
extern "C" void kernel_launch(void* const* d_in, const int* in_sizes, int n_in,
                              void* d_out, int out_size, void* d_ws, size_t ws_size,
                              hipStream_t stream) {
    const float* cur  = (const float*)d_in[0];
    const float* hist = (const float*)d_in[1];
    const float* feat = (const float*)d_in[2];
    float* out = (float*)d_out;   // labels[32768] ++ loss[1]

    char* ws = (char*)d_ws;
    bf16*  fhat    = (bf16*)ws;                           // 16 MiB
    float* negbuf  = (float*)(ws + 16777216);             // 32768 f32 (compacted fg rows)
    float* posdot  = (float*)(ws + 16908288);             // 32768 f32
    unsigned short* fgidx = (unsigned short*)(ws + 17039360);  // 32768 u16
    unsigned short* bgidx = (unsigned short*)(ws + 17104896);  // 32768 u16
    float* flag    = (float*)(ws + 17170432);             // 8 f32
    int*   nfg     = (int*)(ws + 17170432 + 64);
    int*   nbg     = nfg + 8;
    float* framebuf = (float*)(nbg + 8);                  // 16 f32

    stats_kernel<<<8, 256, 0, stream>>>(cur, hist, flag, nfg, nbg);
    labels_kernel<<<8, 1024, 0, stream>>>(cur, hist, flag, out, negbuf, fgidx, bgidx, nfg, nbg);
    normalize_kernel<<<512, 256, 0, stream>>>(feat, fhat, posdot);
    dim3 g(32, 32, 8);
    sim_kernel<<<g, 256, 0, stream>>>(fhat, fgidx, bgidx, nfg, nbg, negbuf);
    loss_frame_kernel<<<8, 256, 0, stream>>>(negbuf, posdot, fgidx, nfg, nbg, framebuf);
    loss_final_kernel<<<1, 64, 0, stream>>>(framebuf, out + 32768);
}